// Round 1
// 326.252 us; speedup vs baseline: 1.0182x; 1.0182x over previous
//
#include <hip/hip_runtime.h>
#include <math.h>

typedef __attribute__((ext_vector_type(8))) short short8;
typedef __attribute__((ext_vector_type(4))) float f32x4;
typedef unsigned short u16;

__device__ __forceinline__ float b2f(u16 u) {
    union { unsigned u; float f; } c; c.u = ((unsigned)u) << 16; return c.f;
}
__device__ __forceinline__ u16 f2b(float f) {
    unsigned u = __float_as_uint(f);
    u += 0x7fffu + ((u >> 16) & 1u);   // RNE
    return (u16)(u >> 16);
}

__device__ __forceinline__ void gl_lds16(const u16* g, u16* l) {
    __builtin_amdgcn_global_load_lds(
        (const __attribute__((address_space(1))) void*)g,
        (__attribute__((address_space(3))) void*)l,
        16, 0, 0);
}

// raw workgroup barrier: no vmcnt/lgkmcnt drain, but a compiler memory fence
// on both sides so glds/ds_read cannot be moved across it.
__device__ __forceinline__ void wgbar() {
    asm volatile("" ::: "memory");
    __builtin_amdgcn_s_barrier();
    asm volatile("" ::: "memory");
}

// fp32 -> bf16 (RNE), n multiple of 8, one thread per 8 elements
__global__ __launch_bounds__(256) void cvt_f32_bf16(const float* __restrict__ src,
                                                    u16* __restrict__ dst, int n) {
    const int i = (blockIdx.x * 256 + threadIdx.x) * 8;
    if (i >= n) return;
    const float4 a = *(const float4*)&src[i];
    const float4 b = *(const float4*)&src[i + 4];
    short8 o;
    o[0] = (short)f2b(a.x); o[1] = (short)f2b(a.y);
    o[2] = (short)f2b(a.z); o[3] = (short)f2b(a.w);
    o[4] = (short)f2b(b.x); o[5] = (short)f2b(b.y);
    o[6] = (short)f2b(b.z); o[7] = (short)f2b(b.w);
    *(short8*)&dst[i] = o;
}

// 4 weight matrices (1M fp32 each) -> contiguous bf16; z selects source
__global__ __launch_bounds__(256) void cvt_weights(
    const float* __restrict__ w0, const float* __restrict__ w1,
    const float* __restrict__ w2, const float* __restrict__ w3,
    u16* __restrict__ dst) {
    const int z = blockIdx.z;
    const float* src = (z == 0) ? w0 : (z == 1) ? w1 : (z == 2) ? w2 : w3;
    const int i = (blockIdx.x * 256 + threadIdx.x) * 8;
    const float4 a = *(const float4*)&src[i];
    const float4 b = *(const float4*)&src[i + 4];
    short8 o;
    o[0] = (short)f2b(a.x); o[1] = (short)f2b(a.y);
    o[2] = (short)f2b(a.z); o[3] = (short)f2b(a.w);
    o[4] = (short)f2b(b.x); o[5] = (short)f2b(b.y);
    o[6] = (short)f2b(b.z); o[7] = (short)f2b(b.w);
    *(short8*)&dst[(long)z * 1024 * 1024 + i] = o;
}

// ---------------------------------------------------------------------------
// 256x256-tile counted-vmcnt GEMM: C[M,N] = scale * A[M,K] @ W[N,K]^T
// bf16 in, fp32 accum. 512 threads = 8 waves (2M x 4N), 128x64 out per wave.
// LDS: 2 double-buffers x 2 k-halves x [256 rows][32 cols] for A and B
// (128 KiB). K-half-split keeps each staged half contiguous for
// global_load_lds AND gives minimum-conflict ds_read_b128 (row stride 64 B,
// slot fq*16 B -> 8 lanes per 4-bank group) with NO swizzle.
// Schedule per half-K phase (2 phases per 64-K tile):
//   12x ds_read_b128 -> issue 4 glds for tile t+1 -> s_waitcnt vmcnt(4)
//   (counted: waits only the loads issued TWO phases earlier; never drains
//   to 0 mid-loop) -> raw s_barrier -> setprio(1) + 32 MFMA + setprio(0).
// Overwrite safety: a half staged in phase (t,h) was last read in phase
// (t-1,h); those reads complete before the reader's MFMA (compiler lgkm),
// which precedes the barrier the stager just crossed.
// ---------------------------------------------------------------------------
template<typename OT>
__device__ __forceinline__ void gemm256_body(
    const u16* __restrict__ A, const u16* __restrict__ W, OT* __restrict__ C,
    int lda, int ldw, int ldc, int K, float scale)
{
    __shared__ u16 lsA[2][2][8192];   // [buf][khalf][256*32]
    __shared__ u16 lsB[2][2][8192];

    const int m0 = blockIdx.y * 256;
    const int n0 = blockIdx.x * 256;
    const int t = threadIdx.x;            // 0..511
    const int lane = t & 63;
    const int w = t >> 6;                 // wave 0..7
    const int wm = (w & 1) * 128;
    const int wn = (w >> 1) * 64;
    const int fr = lane & 15;
    const int fq = lane >> 4;

    // staging: glds j covers khalf elems j*4096 + t*8
    //  -> row = j*128 + t/4, col = (t&3)*8 (linear LDS, linear source)
    const int srow = t >> 2;
    const int scol = (t & 3) * 8;
    const u16* pA0 = A + (long)(m0 + srow) * lda + scol;
    const u16* pA1 = A + (long)(m0 + 128 + srow) * lda + scol;
    const u16* pW0 = W + (long)(n0 + srow) * ldw + scol;
    const u16* pW1 = W + (long)(n0 + 128 + srow) * ldw + scol;
    const int tld = t * 8;

    f32x4 acc[8][4];
#pragma unroll
    for (int i = 0; i < 8; ++i)
#pragma unroll
        for (int j = 0; j < 4; ++j)
            acc[i][j] = (f32x4){0.f, 0.f, 0.f, 0.f};

    const int aoff = (wm + fr) * 32 + fq * 8;   // elems within a khalf array
    const int boff = (wn + fr) * 32 + fq * 8;

#define STAGE256(buf, h, ko) do { \
    gl_lds16(pA0 + (ko), &lsA[buf][h][tld]); \
    gl_lds16(pA1 + (ko), &lsA[buf][h][4096 + tld]); \
    gl_lds16(pW0 + (ko), &lsB[buf][h][tld]); \
    gl_lds16(pW1 + (ko), &lsB[buf][h][4096 + tld]); \
} while (0)

    const int nt = K >> 6;
    // prologue: tile 0, both k-halves (8 loads); wait first half (vmcnt 4)
    STAGE256(0, 0, 0);
    STAGE256(0, 1, 32);
    asm volatile("s_waitcnt vmcnt(4)" ::: "memory");
    wgbar();

    for (int tt = 0; tt < nt; ++tt) {
        const int p = tt & 1;
        const int kn = (tt + 1) << 6;
#pragma unroll
        for (int h = 0; h < 2; ++h) {
            short8 af[8], bfr[4];
#pragma unroll
            for (int m = 0; m < 8; ++m)
                af[m] = *(const short8*)&lsA[p][h][aoff + m * 512];
#pragma unroll
            for (int n = 0; n < 4; ++n)
                bfr[n] = *(const short8*)&lsB[p][h][boff + n * 512];
            if (tt + 1 < nt) {
                STAGE256(p ^ 1, h, kn + h * 32);
                // outstanding = 8 (prev phase's half + this phase's half);
                // wait oldest 4 -> data for NEXT phase's ds_reads is in LDS
                asm volatile("s_waitcnt vmcnt(4)" ::: "memory");
            } else {
                asm volatile("s_waitcnt vmcnt(0)" ::: "memory");
            }
            wgbar();
            __builtin_amdgcn_s_setprio(1);
#pragma unroll
            for (int m = 0; m < 8; ++m)
#pragma unroll
                for (int n = 0; n < 4; ++n)
                    acc[m][n] = __builtin_amdgcn_mfma_f32_16x16x32_bf16(
                        af[m], bfr[n], acc[m][n], 0, 0, 0);
            __builtin_amdgcn_s_setprio(0);
        }
    }
#undef STAGE256

    // C/D layout: col = lane&15, row = quad*4 + reg  [verified m89/m91]
#pragma unroll
    for (int m = 0; m < 8; ++m) {
        const int row0 = m0 + wm + m * 16 + fq * 4;
#pragma unroll
        for (int n = 0; n < 4; ++n) {
            const int col = n0 + wn + n * 16 + fr;
#pragma unroll
            for (int r = 0; r < 4; ++r) {
                const float val = acc[m][n][r] * scale;
                if (sizeof(OT) == 2) {
                    ((u16*)C)[(long)(row0 + r) * ldc + col] = f2b(val);
                } else {
                    ((float*)C)[(long)(row0 + r) * ldc + col] = val;
                }
            }
        }
    }
}

template<typename OT>
__global__ __launch_bounds__(512, 2) void gemm256_bt(
    const u16* __restrict__ A, const u16* __restrict__ W, OT* __restrict__ C,
    int lda, int ldw, int ldc, int K,
    long sA, long sW, long sC, float scale)
{
    const int z = blockIdx.z;
    gemm256_body<OT>(A + (long)z * sA, W + (long)z * sW, C + (long)z * sC,
                     lda, ldw, ldc, K, scale);
}

// dual GEMM: z<4 -> scores batch z; z>=4 -> UT batch z-4 (only y<4 blocks)
__global__ __launch_bounds__(512, 2) void gemm256_dual(
    const u16* __restrict__ A0, const u16* __restrict__ W0, u16* __restrict__ C0,
    int lda0, int ldw0, int ldc0, long sA0, long sW0, long sC0, float scale0,
    const u16* __restrict__ A1, const u16* __restrict__ W1, u16* __restrict__ C1,
    int lda1, int ldw1, int ldc1, long sA1, long sW1, long sC1, float scale1)
{
    const int z = blockIdx.z;
    const u16 *A, *W; u16 *C; int lda, ldw, ldc; float scl;
    if (z < 4) {
        A = A0 + (long)z * sA0; W = W0 + (long)z * sW0; C = C0 + (long)z * sC0;
        lda = lda0; ldw = ldw0; ldc = ldc0; scl = scale0;
    } else {
        if (blockIdx.y >= 4) return;   // uniform early-exit, before any barrier
        const int b = z - 4;
        A = A1 + (long)b * sA1; W = W1 + (long)b * sW1; C = C1 + (long)b * sC1;
        lda = lda1; ldw = ldw1; ldc = ldc1; scl = scale1;
    }
    gemm256_body<u16>(A, W, C, lda, ldw, ldc, 1024, scl);
}

// ---------------------------------------------------------------------------
// 128x128-tile GEMM (previous structure) — retained for PV, whose 256² grid
// would be only 128 blocks (half the GPU idle).
// ---------------------------------------------------------------------------
template<typename OT>
__device__ __forceinline__ void gemm_body(
    const u16* __restrict__ A, const u16* __restrict__ W, OT* __restrict__ C,
    int lda, int ldw, int ldc, int K, float scale)
{
    __shared__ u16 lsA[2][128 * 32];
    __shared__ u16 lsB[2][128 * 32];

    const int m0 = blockIdx.y * 128;
    const int n0 = blockIdx.x * 128;
    const int t = threadIdx.x;
    const int lane = t & 63;
    const int wave = t >> 6;
    const int wm = (wave & 1) * 64;
    const int wn = (wave >> 1) * 64;

    const int sr = t >> 2;
    const int scol = ((t & 3) ^ ((t >> 3) & 3)) * 8;

    const u16* pa0 = A + (long)(m0 + sr) * lda + scol;
    const u16* pa1 = pa0 + (long)64 * lda;
    const u16* pw0 = W + (long)(n0 + sr) * ldw + scol;
    const u16* pw1 = pw0 + (long)64 * ldw;

    f32x4 acc[4][4];
#pragma unroll
    for (int i = 0; i < 4; ++i)
#pragma unroll
        for (int j = 0; j < 4; ++j)
            acc[i][j] = (f32x4){0.f, 0.f, 0.f, 0.f};

    const int fr = lane & 15;
    const int fq = lane >> 4;
    const int swz = (fq ^ ((fr >> 1) & 3)) * 8;
    const int aoff = (wm + fr) * 32 + swz;
    const int boff = (wn + fr) * 32 + swz;

    gl_lds16(pa0, &lsA[0][t * 8]);        pa0 += 32;
    gl_lds16(pa1, &lsA[0][2048 + t * 8]); pa1 += 32;
    gl_lds16(pw0, &lsB[0][t * 8]);        pw0 += 32;
    gl_lds16(pw1, &lsB[0][2048 + t * 8]); pw1 += 32;

    const int nsteps = K >> 5;
    int par = 0;
    for (int s = 0; s < nsteps; ++s) {
        __syncthreads();
        if (s + 1 < nsteps) {
            const int np = par ^ 1;
            gl_lds16(pa0, &lsA[np][t * 8]);        pa0 += 32;
            gl_lds16(pa1, &lsA[np][2048 + t * 8]); pa1 += 32;
            gl_lds16(pw0, &lsB[np][t * 8]);        pw0 += 32;
            gl_lds16(pw1, &lsB[np][2048 + t * 8]); pw1 += 32;
        }

        short8 af[4], bf[4];
#pragma unroll
        for (int i = 0; i < 4; ++i)
            af[i] = *(const short8*)&lsA[par][aoff + i * 512];
#pragma unroll
        for (int j = 0; j < 4; ++j)
            bf[j] = *(const short8*)&lsB[par][boff + j * 512];
#pragma unroll
        for (int i = 0; i < 4; ++i)
#pragma unroll
            for (int j = 0; j < 4; ++j)
                acc[i][j] = __builtin_amdgcn_mfma_f32_16x16x32_bf16(af[i], bf[j], acc[i][j], 0, 0, 0);
        par ^= 1;
    }

#pragma unroll
    for (int i = 0; i < 4; ++i) {
#pragma unroll
        for (int j = 0; j < 4; ++j) {
            const int row0 = m0 + wm + i * 16 + fq * 4;
            const int col = n0 + wn + j * 16 + fr;
#pragma unroll
            for (int r = 0; r < 4; ++r) {
                const int row = row0 + r;
                const float val = acc[i][j][r] * scale;
                if (sizeof(OT) == 2) {
                    ((u16*)C)[(long)row * ldc + col] = f2b(val);
                } else {
                    ((float*)C)[(long)row * ldc + col] = val;
                }
            }
        }
    }
}

template<typename OT>
__global__ __launch_bounds__(256) void gemm_bt(
    const u16* __restrict__ A, const u16* __restrict__ W, OT* __restrict__ C,
    int lda, int ldw, int ldc, int K,
    long sA, long sW, long sC, float scale)
{
    const int bz = blockIdx.z;
    gemm_body<OT>(A + (long)bz * sA, W + (long)bz * sW, C + (long)bz * sC,
                  lda, ldw, ldc, K, scale);
}

// interleaved RoPE in-place on q and k: rows = b*2048+s, 512 pairs per row
__global__ __launch_bounds__(256) void rope_kernel(u16* q, u16* k) {
    const int row = blockIdx.x;
    const int pos = row & 2047;
    u16* p = (blockIdx.y ? k : q) + (long)row * 1024;
#pragma unroll
    for (int it = 0; it < 2; ++it) {
        const int i = threadIdx.x + it * 256;
        const float e = (float)i * (1.0f / 512.0f);
        const float inv = powf(10000.0f, -e);
        const float ang = (float)pos * inv;
        float s, c;
        sincosf(ang, &s, &c);
        const float xr = b2f(p[2 * i]);
        const float xi = b2f(p[2 * i + 1]);
        p[2 * i]     = f2b(xr * c - xi * s);
        p[2 * i + 1] = f2b(xr * s + xi * c);
    }
}

// row-wise softmax over 2048 bf16 entries, in-place safe; one block per row
__global__ __launch_bounds__(256) void softmax_kernel(const u16* __restrict__ S, u16* __restrict__ P) {
    const long row = blockIdx.x;
    const u16* src = S + row * 2048;
    u16* dst = P + row * 2048;
    const int t = threadIdx.x;
    const int lane = t & 63;
    const int wave = t >> 6;
    __shared__ float red[4];

    float v[8];
    const short8 raw = *(const short8*)&src[t * 8];
#pragma unroll
    for (int i = 0; i < 8; ++i) v[i] = b2f((u16)raw[i]);

    float m = v[0];
#pragma unroll
    for (int i = 1; i < 8; ++i) m = fmaxf(m, v[i]);
    for (int o = 32; o > 0; o >>= 1) m = fmaxf(m, __shfl_xor(m, o, 64));
    if (lane == 0) red[wave] = m;
    __syncthreads();
    m = fmaxf(fmaxf(red[0], red[1]), fmaxf(red[2], red[3]));
    __syncthreads();

    float sum = 0.f;
#pragma unroll
    for (int i = 0; i < 8; ++i) { v[i] = expf(v[i] - m); sum += v[i]; }
    for (int o = 32; o > 0; o >>= 1) sum += __shfl_xor(sum, o, 64);
    if (lane == 0) red[wave] = sum;
    __syncthreads();
    sum = red[0] + red[1] + red[2] + red[3];
    const float is = 1.0f / sum;

    short8 outv;
#pragma unroll
    for (int i = 0; i < 8; ++i) outv[i] = (short)f2b(v[i] * is);
    *(short8*)&dst[t * 8] = outv;
}

extern "C" void kernel_launch(void* const* d_in, const int* in_sizes, int n_in,
                              void* d_out, int out_size, void* d_ws, size_t ws_size,
                              hipStream_t stream)
{
    (void)in_sizes; (void)n_in; (void)out_size; (void)ws_size;
    const float* x  = (const float*)d_in[0];
    const float* wq = (const float*)d_in[1];
    const float* wk = (const float*)d_in[2];
    const float* wv = (const float*)d_in[3];
    const float* wo = (const float*)d_in[4];
    float* out = (float*)d_out;

    // workspace layout (bf16 elements), 104 MB total
    const long M1 = 1024 * 1024;
    u16* ws  = (u16*)d_ws;
    u16* xb  = ws;               // [8192][1024] bf16 x; reused as UT after QKV
    u16* wqb = xb + 8 * M1;      // [4][1024][1024] wq,wk,wv,wo contiguous
    u16* wob = wqb + 3 * M1;
    u16* q   = wqb + 4 * M1;     // [8192][1024]; kk, v contiguous after (z-strided)
    u16* kk  = q + 8 * M1;
    u16* v   = kk + 8 * M1;
    u16* sc  = v + 8 * M1;       // [4][2048][2048], softmax in-place
    u16* UT  = xb;               // alias: [4][1024][2048], xb dead after QKV

    const dim3 blk(256);
    const dim3 blk5(512);

    // fp32 -> bf16 conversions (2 dispatches)
    cvt_f32_bf16<<<dim3(4096), blk, 0, stream>>>(x, xb, 8 * 1024 * 1024);
    cvt_weights<<<dim3(512, 1, 4), blk, 0, stream>>>(wq, wk, wv, wo, wqb);

    // QKV fused on 256² counted-vmcnt kernel: z in {0,1,2} -> q, k, v
    // (M=8192, N=1024, K=1024) -> grid (4, 32, 3) = 384 blocks
    gemm256_bt<u16><<<dim3(4, 32, 3), blk5, 0, stream>>>(xb, wqb, q,
        1024, 1024, 1024, 1024, 0, M1, 8 * M1, 1.0f);

    rope_kernel<<<dim3(8192, 2), blk, 0, stream>>>(q, kk);

    // fused on 256² kernel: scores = q @ k^T / 32 (M=N=2048, K=1024, z=0..3)
    //                     + UT[b][e][k] = wo @ v[b]^T (M=1024, z=4..7, y<4)
    gemm256_dual<<<dim3(8, 8, 8), blk5, 0, stream>>>(
        q, kk, sc, 1024, 1024, 2048, 2 * M1, 2 * M1, 4 * M1, 0.03125f,
        wob, v, UT, 1024, 1024, 2048, 0, 2 * M1, 2 * M1, 1.0f);

    softmax_kernel<<<dim3(8192), blk, 0, stream>>>(sc, sc);

    // out[b] = P[b] @ UT[b]^T   (M=2048, N=1024, K=2048), fp32 output
    // stays on 128² kernel: 512 blocks = full GPU (256² grid would be 128)
    gemm_bt<float><<<dim3(8, 16, 4), blk, 0, stream>>>(sc, UT, out,
        2048, 2048, 1024, 2048, 4 * M1, 2 * M1, 2 * M1, 1.0f);
}

// Round 2
// 323.070 us; speedup vs baseline: 1.0283x; 1.0098x over previous
//
#include <hip/hip_runtime.h>
#include <math.h>

typedef __attribute__((ext_vector_type(8))) short short8;
typedef __attribute__((ext_vector_type(4))) float f32x4;
typedef unsigned short u16;

__device__ __forceinline__ float b2f(u16 u) {
    union { unsigned u; float f; } c; c.u = ((unsigned)u) << 16; return c.f;
}
__device__ __forceinline__ u16 f2b(float f) {
    unsigned u = __float_as_uint(f);
    u += 0x7fffu + ((u >> 16) & 1u);   // RNE
    return (u16)(u >> 16);
}

__device__ __forceinline__ void gl_lds16(const u16* g, u16* l) {
    __builtin_amdgcn_global_load_lds(
        (const __attribute__((address_space(1))) void*)g,
        (__attribute__((address_space(3))) void*)l,
        16, 0, 0);
}

// fp32 -> bf16 (RNE), n multiple of 8, one thread per 8 elements
__global__ __launch_bounds__(256) void cvt_f32_bf16(const float* __restrict__ src,
                                                    u16* __restrict__ dst, int n) {
    const int i = (blockIdx.x * 256 + threadIdx.x) * 8;
    if (i >= n) return;
    const float4 a = *(const float4*)&src[i];
    const float4 b = *(const float4*)&src[i + 4];
    short8 o;
    o[0] = (short)f2b(a.x); o[1] = (short)f2b(a.y);
    o[2] = (short)f2b(a.z); o[3] = (short)f2b(a.w);
    o[4] = (short)f2b(b.x); o[5] = (short)f2b(b.y);
    o[6] = (short)f2b(b.z); o[7] = (short)f2b(b.w);
    *(short8*)&dst[i] = o;
}

// 4 weight matrices (1M fp32 each) -> contiguous bf16; z selects source
__global__ __launch_bounds__(256) void cvt_weights(
    const float* __restrict__ w0, const float* __restrict__ w1,
    const float* __restrict__ w2, const float* __restrict__ w3,
    u16* __restrict__ dst) {
    const int z = blockIdx.z;
    const float* src = (z == 0) ? w0 : (z == 1) ? w1 : (z == 2) ? w2 : w3;
    const int i = (blockIdx.x * 256 + threadIdx.x) * 8;
    const float4 a = *(const float4*)&src[i];
    const float4 b = *(const float4*)&src[i + 4];
    short8 o;
    o[0] = (short)f2b(a.x); o[1] = (short)f2b(a.y);
    o[2] = (short)f2b(a.z); o[3] = (short)f2b(a.w);
    o[4] = (short)f2b(b.x); o[5] = (short)f2b(b.y);
    o[6] = (short)f2b(b.z); o[7] = (short)f2b(b.w);
    *(short8*)&dst[(long)z * 1024 * 1024 + i] = o;
}

// ---------------------------------------------------------------------------
// 256x256-tile ring-4 counted-vmcnt GEMM: C[M,N] = scale * A[M,K] @ W[N,K]^T
// bf16 in, fp32 accum. 512 threads = 8 waves (2M x 4N), 128x64 out per wave.
//
// K is processed as 32-col subtiles st = 0..K/32-1 through a 4-slot LDS ring
// (A slot: 256x32, B slot: 256x32; 4 slots = 128 KiB total). Prefetch depth
// 3 subtiles -> steady-state s_waitcnt vmcnt(8) confirms the subtile needed
// NEXT phase while leaving 8 loads (2 subtiles) in flight: every load gets
// TWO full compute phases of latency slack (R1 had one).
//
// R2 fix: XOR swizzle restored (R1 dropped it -> 4.7M bank conflicts).
// Staging uses pre-swizzled GLOBAL source + linear LDS dest (rule #21):
//   LDS[row][slot s] = global[row][s ^ ((row>>1)&3)]
// Reads use slot fq ^ ((fr>>1)&3)  -> composes to identity; consecutive
// 8-lane groups hit 8 distinct 4-bank clusters -> 0 conflicts (proven
// formula from the 128-tile kernel, measured 0).
//
// Ring-4 overwrite safety: stage(st+3) at phase st overwrites the slot read
// at phase st-1; lgkmcnt(0) BEFORE each barrier drains those ds_reads, and
// the stager issues only after crossing that barrier.
// ---------------------------------------------------------------------------
template<typename OT>
__device__ __forceinline__ void gemm256_body(
    const u16* __restrict__ A, const u16* __restrict__ W, OT* __restrict__ C,
    int lda, int ldw, int ldc, int K, float scale)
{
    __shared__ u16 lsA[4 * 8192];   // [slot][256 rows][32 cols]
    __shared__ u16 lsB[4 * 8192];

    const int m0 = blockIdx.y * 256;
    const int n0 = blockIdx.x * 256;
    const int t = threadIdx.x;            // 0..511
    const int lane = t & 63;
    const int w = t >> 6;                 // wave 0..7
    const int wm = (w & 1) * 128;
    const int wn = (w >> 1) * 64;
    const int fr = lane & 15;
    const int fq = lane >> 4;

    // staging: thread t covers row srow = t>>2 of each 128-row half,
    // LDS slot (t&3); global col-slot pre-swizzled so that
    // LDS[row][s] = global[row][s ^ ((row>>1)&3)]
    const int srow = t >> 2;
    const int scol = ((t & 3) ^ ((t >> 3) & 3)) * 8;
    const u16* pA0 = A + (long)(m0 + srow) * lda + scol;
    const u16* pA1 = A + (long)(m0 + 128 + srow) * lda + scol;
    const u16* pW0 = W + (long)(n0 + srow) * ldw + scol;
    const u16* pW1 = W + (long)(n0 + 128 + srow) * ldw + scol;
    const int tld = t * 8;

    f32x4 acc[8][4];
#pragma unroll
    for (int i = 0; i < 8; ++i)
#pragma unroll
        for (int j = 0; j < 4; ++j)
            acc[i][j] = (f32x4){0.f, 0.f, 0.f, 0.f};

    // fragment read offsets: row*32 + swizzled 16B slot
    const int swz = (fq ^ ((fr >> 1) & 3)) * 8;
    const int aoff = (wm + fr) * 32 + swz;
    const int boff = (wn + fr) * 32 + swz;

#define STAGE256(s) do { \
    const int _sl = ((s) & 3) * 8192; const int _ko = (s) * 32; \
    gl_lds16(pA0 + _ko, &lsA[_sl + tld]); \
    gl_lds16(pA1 + _ko, &lsA[_sl + 4096 + tld]); \
    gl_lds16(pW0 + _ko, &lsB[_sl + tld]); \
    gl_lds16(pW1 + _ko, &lsB[_sl + 4096 + tld]); \
} while (0)

    const int n2 = K >> 5;   // number of 32-col subtiles

    // prologue: fill 3 ring slots (12 loads); confirm subtile 0 (oldest 4)
    STAGE256(0);
    STAGE256(1);
    STAGE256(2);
    asm volatile("s_waitcnt vmcnt(8)" ::: "memory");
    __builtin_amdgcn_s_barrier();
    __builtin_amdgcn_sched_barrier(0);

    for (int st = 0; st < n2; ++st) {
        const int slot = (st & 3) * 8192;
        short8 af[8], bfr[4];
#pragma unroll
        for (int m = 0; m < 8; ++m)
            af[m] = *(const short8*)&lsA[slot + aoff + m * 512];
#pragma unroll
        for (int n = 0; n < 4; ++n)
            bfr[n] = *(const short8*)&lsB[slot + boff + n * 512];

        if (st + 3 < n2) {
            STAGE256(st + 3);
            // in flight: subtiles st+1, st+2, st+3 (12 loads); confirm st+1
            asm volatile("s_waitcnt vmcnt(8)" ::: "memory");
        } else if (st + 2 < n2) {
            // in flight: st+1, st+2 (8); confirm st+1
            asm volatile("s_waitcnt vmcnt(4)" ::: "memory");
        } else if (st + 1 < n2) {
            // in flight: st+1 (4); confirm it
            asm volatile("s_waitcnt vmcnt(0)" ::: "memory");
        }
        // drain this phase's ds_reads so the slot overwritten next phase
        // (read one phase ago) is provably quiescent after the barrier
        asm volatile("s_waitcnt lgkmcnt(0)" ::: "memory");
        __builtin_amdgcn_s_barrier();
        __builtin_amdgcn_sched_barrier(0);

        __builtin_amdgcn_s_setprio(1);
#pragma unroll
        for (int m = 0; m < 8; ++m)
#pragma unroll
            for (int n = 0; n < 4; ++n)
                acc[m][n] = __builtin_amdgcn_mfma_f32_16x16x32_bf16(
                    af[m], bfr[n], acc[m][n], 0, 0, 0);
        __builtin_amdgcn_s_setprio(0);
    }
#undef STAGE256

    // C/D layout: col = lane&15, row = quad*4 + reg  [verified m89/m91]
#pragma unroll
    for (int m = 0; m < 8; ++m) {
        const int row0 = m0 + wm + m * 16 + fq * 4;
#pragma unroll
        for (int n = 0; n < 4; ++n) {
            const int col = n0 + wn + n * 16 + fr;
#pragma unroll
            for (int r = 0; r < 4; ++r) {
                const float val = acc[m][n][r] * scale;
                if (sizeof(OT) == 2) {
                    ((u16*)C)[(long)(row0 + r) * ldc + col] = f2b(val);
                } else {
                    ((float*)C)[(long)(row0 + r) * ldc + col] = val;
                }
            }
        }
    }
}

template<typename OT>
__global__ __launch_bounds__(512, 2) void gemm256_bt(
    const u16* __restrict__ A, const u16* __restrict__ W, OT* __restrict__ C,
    int lda, int ldw, int ldc, int K,
    long sA, long sW, long sC, float scale)
{
    const int z = blockIdx.z;
    gemm256_body<OT>(A + (long)z * sA, W + (long)z * sW, C + (long)z * sC,
                     lda, ldw, ldc, K, scale);
}

// dual GEMM: z<4 -> scores batch z; z>=4 -> UT batch z-4 (only y<4 blocks)
__global__ __launch_bounds__(512, 2) void gemm256_dual(
    const u16* __restrict__ A0, const u16* __restrict__ W0, u16* __restrict__ C0,
    int lda0, int ldw0, int ldc0, long sA0, long sW0, long sC0, float scale0,
    const u16* __restrict__ A1, const u16* __restrict__ W1, u16* __restrict__ C1,
    int lda1, int ldw1, int ldc1, long sA1, long sW1, long sC1, float scale1)
{
    const int z = blockIdx.z;
    const u16 *A, *W; u16 *C; int lda, ldw, ldc; float scl;
    if (z < 4) {
        A = A0 + (long)z * sA0; W = W0 + (long)z * sW0; C = C0 + (long)z * sC0;
        lda = lda0; ldw = ldw0; ldc = ldc0; scl = scale0;
    } else {
        if (blockIdx.y >= 4) return;   // uniform early-exit, before any barrier
        const int b = z - 4;
        A = A1 + (long)b * sA1; W = W1 + (long)b * sW1; C = C1 + (long)b * sC1;
        lda = lda1; ldw = ldw1; ldc = ldc1; scl = scale1;
    }
    gemm256_body<u16>(A, W, C, lda, ldw, ldc, 1024, scl);
}

// ---------------------------------------------------------------------------
// 128x128-tile GEMM (previous structure) — retained for PV, whose 256² grid
// would be only 128 blocks (half the GPU idle).
// ---------------------------------------------------------------------------
template<typename OT>
__device__ __forceinline__ void gemm_body(
    const u16* __restrict__ A, const u16* __restrict__ W, OT* __restrict__ C,
    int lda, int ldw, int ldc, int K, float scale)
{
    __shared__ u16 lsA[2][128 * 32];
    __shared__ u16 lsB[2][128 * 32];

    const int m0 = blockIdx.y * 128;
    const int n0 = blockIdx.x * 128;
    const int t = threadIdx.x;
    const int lane = t & 63;
    const int wave = t >> 6;
    const int wm = (wave & 1) * 64;
    const int wn = (wave >> 1) * 64;

    const int sr = t >> 2;
    const int scol = ((t & 3) ^ ((t >> 3) & 3)) * 8;

    const u16* pa0 = A + (long)(m0 + sr) * lda + scol;
    const u16* pa1 = pa0 + (long)64 * lda;
    const u16* pw0 = W + (long)(n0 + sr) * ldw + scol;
    const u16* pw1 = pw0 + (long)64 * ldw;

    f32x4 acc[4][4];
#pragma unroll
    for (int i = 0; i < 4; ++i)
#pragma unroll
        for (int j = 0; j < 4; ++j)
            acc[i][j] = (f32x4){0.f, 0.f, 0.f, 0.f};

    const int fr = lane & 15;
    const int fq = lane >> 4;
    const int swz = (fq ^ ((fr >> 1) & 3)) * 8;
    const int aoff = (wm + fr) * 32 + swz;
    const int boff = (wn + fr) * 32 + swz;

    gl_lds16(pa0, &lsA[0][t * 8]);        pa0 += 32;
    gl_lds16(pa1, &lsA[0][2048 + t * 8]); pa1 += 32;
    gl_lds16(pw0, &lsB[0][t * 8]);        pw0 += 32;
    gl_lds16(pw1, &lsB[0][2048 + t * 8]); pw1 += 32;

    const int nsteps = K >> 5;
    int par = 0;
    for (int s = 0; s < nsteps; ++s) {
        __syncthreads();
        if (s + 1 < nsteps) {
            const int np = par ^ 1;
            gl_lds16(pa0, &lsA[np][t * 8]);        pa0 += 32;
            gl_lds16(pa1, &lsA[np][2048 + t * 8]); pa1 += 32;
            gl_lds16(pw0, &lsB[np][t * 8]);        pw0 += 32;
            gl_lds16(pw1, &lsB[np][2048 + t * 8]); pw1 += 32;
        }

        short8 af[4], bf[4];
#pragma unroll
        for (int i = 0; i < 4; ++i)
            af[i] = *(const short8*)&lsA[par][aoff + i * 512];
#pragma unroll
        for (int j = 0; j < 4; ++j)
            bf[j] = *(const short8*)&lsB[par][boff + j * 512];
#pragma unroll
        for (int i = 0; i < 4; ++i)
#pragma unroll
            for (int j = 0; j < 4; ++j)
                acc[i][j] = __builtin_amdgcn_mfma_f32_16x16x32_bf16(af[i], bf[j], acc[i][j], 0, 0, 0);
        par ^= 1;
    }

#pragma unroll
    for (int i = 0; i < 4; ++i) {
#pragma unroll
        for (int j = 0; j < 4; ++j) {
            const int row0 = m0 + wm + i * 16 + fq * 4;
            const int col = n0 + wn + j * 16 + fr;
#pragma unroll
            for (int r = 0; r < 4; ++r) {
                const int row = row0 + r;
                const float val = acc[i][j][r] * scale;
                if (sizeof(OT) == 2) {
                    ((u16*)C)[(long)row * ldc + col] = f2b(val);
                } else {
                    ((float*)C)[(long)row * ldc + col] = val;
                }
            }
        }
    }
}

template<typename OT>
__global__ __launch_bounds__(256) void gemm_bt(
    const u16* __restrict__ A, const u16* __restrict__ W, OT* __restrict__ C,
    int lda, int ldw, int ldc, int K,
    long sA, long sW, long sC, float scale)
{
    const int bz = blockIdx.z;
    gemm_body<OT>(A + (long)bz * sA, W + (long)bz * sW, C + (long)bz * sC,
                  lda, ldw, ldc, K, scale);
}

// interleaved RoPE in-place on q and k: rows = b*2048+s, 512 pairs per row
__global__ __launch_bounds__(256) void rope_kernel(u16* q, u16* k) {
    const int row = blockIdx.x;
    const int pos = row & 2047;
    u16* p = (blockIdx.y ? k : q) + (long)row * 1024;
#pragma unroll
    for (int it = 0; it < 2; ++it) {
        const int i = threadIdx.x + it * 256;
        const float e = (float)i * (1.0f / 512.0f);
        const float inv = powf(10000.0f, -e);
        const float ang = (float)pos * inv;
        float s, c;
        sincosf(ang, &s, &c);
        const float xr = b2f(p[2 * i]);
        const float xi = b2f(p[2 * i + 1]);
        p[2 * i]     = f2b(xr * c - xi * s);
        p[2 * i + 1] = f2b(xr * s + xi * c);
    }
}

// row-wise softmax over 2048 bf16 entries, in-place safe; one block per row
__global__ __launch_bounds__(256) void softmax_kernel(const u16* __restrict__ S, u16* __restrict__ P) {
    const long row = blockIdx.x;
    const u16* src = S + row * 2048;
    u16* dst = P + row * 2048;
    const int t = threadIdx.x;
    const int lane = t & 63;
    const int wave = t >> 6;
    __shared__ float red[4];

    float v[8];
    const short8 raw = *(const short8*)&src[t * 8];
#pragma unroll
    for (int i = 0; i < 8; ++i) v[i] = b2f((u16)raw[i]);

    float m = v[0];
#pragma unroll
    for (int i = 1; i < 8; ++i) m = fmaxf(m, v[i]);
    for (int o = 32; o > 0; o >>= 1) m = fmaxf(m, __shfl_xor(m, o, 64));
    if (lane == 0) red[wave] = m;
    __syncthreads();
    m = fmaxf(fmaxf(red[0], red[1]), fmaxf(red[2], red[3]));
    __syncthreads();

    float sum = 0.f;
#pragma unroll
    for (int i = 0; i < 8; ++i) { v[i] = expf(v[i] - m); sum += v[i]; }
    for (int o = 32; o > 0; o >>= 1) sum += __shfl_xor(sum, o, 64);
    if (lane == 0) red[wave] = sum;
    __syncthreads();
    sum = red[0] + red[1] + red[2] + red[3];
    const float is = 1.0f / sum;

    short8 outv;
#pragma unroll
    for (int i = 0; i < 8; ++i) outv[i] = (short)f2b(v[i] * is);
    *(short8*)&dst[t * 8] = outv;
}

extern "C" void kernel_launch(void* const* d_in, const int* in_sizes, int n_in,
                              void* d_out, int out_size, void* d_ws, size_t ws_size,
                              hipStream_t stream)
{
    (void)in_sizes; (void)n_in; (void)out_size; (void)ws_size;
    const float* x  = (const float*)d_in[0];
    const float* wq = (const float*)d_in[1];
    const float* wk = (const float*)d_in[2];
    const float* wv = (const float*)d_in[3];
    const float* wo = (const float*)d_in[4];
    float* out = (float*)d_out;

    // workspace layout (bf16 elements), 104 MB total
    const long M1 = 1024 * 1024;
    u16* ws  = (u16*)d_ws;
    u16* xb  = ws;               // [8192][1024] bf16 x; reused as UT after QKV
    u16* wqb = xb + 8 * M1;      // [4][1024][1024] wq,wk,wv,wo contiguous
    u16* wob = wqb + 3 * M1;
    u16* q   = wqb + 4 * M1;     // [8192][1024]; kk, v contiguous after (z-strided)
    u16* kk  = q + 8 * M1;
    u16* v   = kk + 8 * M1;
    u16* sc  = v + 8 * M1;       // [4][2048][2048], softmax in-place
    u16* UT  = xb;               // alias: [4][1024][2048], xb dead after QKV

    const dim3 blk(256);
    const dim3 blk5(512);

    // fp32 -> bf16 conversions (2 dispatches)
    cvt_f32_bf16<<<dim3(4096), blk, 0, stream>>>(x, xb, 8 * 1024 * 1024);
    cvt_weights<<<dim3(512, 1, 4), blk, 0, stream>>>(wq, wk, wv, wo, wqb);

    // QKV fused on 256² ring-4 kernel: z in {0,1,2} -> q, k, v
    // (M=8192, N=1024, K=1024) -> grid (4, 32, 3) = 384 blocks
    gemm256_bt<u16><<<dim3(4, 32, 3), blk5, 0, stream>>>(xb, wqb, q,
        1024, 1024, 1024, 1024, 0, M1, 8 * M1, 1.0f);

    rope_kernel<<<dim3(8192, 2), blk, 0, stream>>>(q, kk);

    // fused on 256² kernel: scores = q @ k^T / 32 (M=N=2048, K=1024, z=0..3)
    //                     + UT[b][e][k] = wo @ v[b]^T (M=1024, z=4..7, y<4)
    gemm256_dual<<<dim3(8, 8, 8), blk5, 0, stream>>>(
        q, kk, sc, 1024, 1024, 2048, 2 * M1, 2 * M1, 4 * M1, 0.03125f,
        wob, v, UT, 1024, 1024, 2048, 0, 2 * M1, 2 * M1, 1.0f);

    softmax_kernel<<<dim3(8192), blk, 0, stream>>>(sc, sc);

    // out[b] = P[b] @ UT[b]^T   (M=2048, N=1024, K=2048), fp32 output
    // stays on 128² kernel: 512 blocks = full GPU (256² grid would be 128)
    gemm_bt<float><<<dim3(8, 16, 4), blk, 0, stream>>>(sc, UT, out,
        2048, 2048, 1024, 2048, 4 * M1, 2 * M1, 2 * M1, 1.0f);
}